// Round 1
// baseline (220.329 us; speedup 1.0000x reference)
//
#include <hip/hip_runtime.h>
#include <cstdint>

// RandomMaskSubgraphs: reproduce JAX reference exactly.
//  - Threefry-2x32-20 PRNG, partitionable counter scheme (bits = y0^y1 of
//    threefry(key_i, (0, j))), key_i = threefry((0,42),(0,i)) computed on host.
//  - k-smallest selection via 2048-bin histogram + exact in-bin ranking
//    with (score, index) stable tie-break (== stable argsort rank < k).
//  - alive/masked state lives directly in d_out as floats (1.0/0.0).

#define NNODES 100000
#define TWON   200000
#define NBINS  2048

__host__ __device__ inline uint32_t rotl32(uint32_t v, int d) {
    return (v << d) | (v >> (32 - d));
}

__host__ __device__ inline void tf2x32(uint32_t k0, uint32_t k1,
                                       uint32_t x0, uint32_t x1,
                                       uint32_t& y0, uint32_t& y1) {
    uint32_t k2 = k0 ^ k1 ^ 0x1BD11BDAu;
    x0 += k0; x1 += k1;
    // 20 rounds: 5 groups of 4, rotations alternate [13,15,26,6]/[17,29,16,24]
    #pragma unroll
    for (int g = 0; g < 5; ++g) {
        const int ra[4] = {13, 15, 26, 6};
        const int rb[4] = {17, 29, 16, 24};
        if ((g & 1) == 0) {
            #pragma unroll
            for (int j = 0; j < 4; ++j) { x0 += x1; x1 = rotl32(x1, ra[j]); x1 ^= x0; }
        } else {
            #pragma unroll
            for (int j = 0; j < 4; ++j) { x0 += x1; x1 = rotl32(x1, rb[j]); x1 ^= x0; }
        }
        // key injection after each group: ks[(g+1)%3], ks[(g+2)%3] + (g+1)
        uint32_t ks[3] = {k0, k1, k2};
        x0 += ks[(g + 1) % 3];
        x1 += ks[(g + 2) % 3] + (uint32_t)(g + 1);
    }
    y0 = x0; y1 = x1;
}

__device__ inline float uniform_from_bits(uint32_t bits) {
    // (bits >> 9) | 0x3f800000 viewed as float, minus 1.0  -> [0,1)
    uint32_t fb = 0x3f800000u | (bits >> 9);
    return __uint_as_float(fb) - 1.0f;
}

__global__ void k_init(float* enc, float* msk, int E,
                       unsigned char* seedA, unsigned char* seedB,
                       unsigned char* cand, int* hist, int* deg, int* scal) {
    int i = blockIdx.x * blockDim.x + threadIdx.x;
    if (i < E) { enc[i] = 1.0f; msk[i] = 0.0f; }
    if (i < TWON) { seedA[i] = 0; seedB[i] = 0; cand[i] = 0; }
    if (i < NBINS) hist[i] = 0;
    if (i < NNODES) deg[i] = 0;
    if (i == 0) { scal[0] = -1; scal[1] = 0; scal[2] = 0; }
}

__global__ void k_seed(const int* seeds, int n, unsigned char* seedA) {
    int i = blockIdx.x * blockDim.x + threadIdx.x;
    if (i < n) seedA[seeds[i]] = 1;
}

__global__ void k_mark(const int* __restrict__ rows, const int* __restrict__ cols,
                       int E, const unsigned char* __restrict__ sm,
                       float* enc, float* msk, unsigned char* cand, int writeCand) {
    int e = blockIdx.x * blockDim.x + threadIdx.x;
    if (e >= E) return;
    int r = rows[e], c = cols[e];
    if (enc[e] != 0.0f && (sm[r] | sm[c])) {
        msk[e] = 1.0f;
        enc[e] = 0.0f;
        if (writeCand) cand[r + c] = 1;  // races write same value: benign
    }
}

__global__ void k_score_hist(const unsigned char* __restrict__ cand,
                             float* __restrict__ scores, int* hist,
                             uint32_t ka, uint32_t kb) {
    int s = blockIdx.x * blockDim.x + threadIdx.x;
    if (s >= TWON) return;
    uint32_t y0, y1;
    tf2x32(ka, kb, 0u, (uint32_t)s, y0, y1);
    float u = uniform_from_bits(y0 ^ y1);
    scores[s] = u;
    if (cand[s]) {
        uint32_t b = (uint32_t)(u * 2048.0f);
        if (b > NBINS - 1) b = NBINS - 1;
        atomicAdd(&hist[b], 1);
    }
}

__global__ void k_scan(int* hist, int* scal, int iter) {
    __shared__ int part[1024];
    __shared__ int sT, sR;
    int t = threadIdx.x;
    int h0 = hist[2 * t];
    int h1 = hist[2 * t + 1];
    part[t] = h0 + h1;
    if (t == 0) { sT = -1; sR = 0; }
    __syncthreads();
    // Hillis-Steele inclusive scan over 1024 pair-sums
    for (int d = 1; d < 1024; d <<= 1) {
        int w = (t >= d) ? part[t - d] : 0;
        __syncthreads();
        part[t] += w;
        __syncthreads();
    }
    int total = part[1023];
    int k = total >> (iter + 1);   // floor(count * 0.5^(i+1)), exact
    int base = (t > 0) ? part[t - 1] : 0;
    if (total > 0) {
        if (h0 > 0 && base <= k && k < base + h0) { sT = 2 * t; sR = k - base; }
        int b2 = base + h0;
        if (h1 > 0 && b2 <= k && k < b2 + h1) { sT = 2 * t + 1; sR = k - b2; }
    }
    __syncthreads();
    if (t == 0) { scal[0] = sT; scal[1] = sR; scal[2] = 0; }
    hist[2 * t] = 0;       // reset for next iteration
    hist[2 * t + 1] = 0;
}

__global__ void k_select(const float* __restrict__ scores, unsigned char* cand,
                         unsigned char* seedB, int* scal, int* list) {
    int s = blockIdx.x * blockDim.x + threadIdx.x;
    if (s >= TWON) return;
    int T = scal[0];
    unsigned char sel = 0;
    if (cand[s]) {
        float u = scores[s];
        int b = (int)(u * 2048.0f);
        if (b > NBINS - 1) b = NBINS - 1;
        if (b < T) sel = 1;
        else if (b == T) {
            int idx = atomicAdd(&scal[2], 1);
            list[idx] = s;   // capacity TWON, can never overflow
        }
        cand[s] = 0;         // reset for next iteration
    }
    seedB[s] = sel;
}

__global__ void k_rank(const float* __restrict__ scores, const int* __restrict__ list,
                       const int* scal, unsigned char* seedB) {
    int n = scal[2];
    int r = scal[1];
    for (int t = threadIdx.x; t < n; t += blockDim.x) {
        int st = list[t];
        float ut = scores[st];
        int rank = 0;
        for (int j = 0; j < n; ++j) {
            int sj = list[j];
            float uj = scores[sj];
            rank += (uj < ut || (uj == ut && sj < st)) ? 1 : 0;
        }
        if (rank < r) seedB[st] = 1;
    }
}

__global__ void k_deg(const int* __restrict__ rows, const float* __restrict__ enc,
                      int E, int* deg) {
    int e = blockIdx.x * blockDim.x + threadIdx.x;
    if (e >= E) return;
    if (enc[e] != 0.0f) atomicAdd(&deg[rows[e]], 1);
}

__global__ void k_dinv(const int* __restrict__ deg, float* __restrict__ dinv) {
    int n = blockIdx.x * blockDim.x + threadIdx.x;
    if (n >= NNODES) return;
    float d = (float)deg[n] + 1e-12f;
    dinv[n] = rsqrtf(d);
}

__global__ void k_out(const int* __restrict__ rows, const int* __restrict__ cols,
                      int E, const float* __restrict__ dinv, float* enc) {
    int e = blockIdx.x * blockDim.x + threadIdx.x;
    if (e >= E) return;
    float a = enc[e];
    if (a != 0.0f) enc[e] = dinv[rows[e]] * dinv[cols[e]];
}

extern "C" void kernel_launch(void* const* d_in, const int* in_sizes, int n_in,
                              void* d_out, int out_size, void* d_ws, size_t ws_size,
                              hipStream_t stream) {
    const int* rows  = (const int*)d_in[0];
    const int* cols  = (const int*)d_in[1];
    // d_in[2] = adj_vals (unused by reference output)
    const int* seeds = (const int*)d_in[3];
    int E      = in_sizes[0];
    int nSeeds = in_sizes[3];

    float* enc = (float*)d_out;     // output 0: enc_vals (doubles as `alive`)
    float* msk = enc + E;           // output 1: masked flags (as 0.0/1.0 floats)

    char* p = (char*)d_ws;
    unsigned char* seedA = (unsigned char*)p; p += TWON;
    unsigned char* seedB = (unsigned char*)p; p += TWON;
    unsigned char* cand  = (unsigned char*)p; p += TWON;
    float* scores = (float*)p; p += TWON * 4;
    int*   hist   = (int*)p;   p += NBINS * 4;
    int*   deg    = (int*)p;   p += NNODES * 4;
    float* dinv   = (float*)p; p += NNODES * 4;
    int*   scal   = (int*)p;   p += 4 * 4;      // [T, r, listCnt, pad]
    int*   list   = (int*)p;   p += TWON * 4;
    // total ws use: ~3.0 MB

    int gE  = (E + 255) / 256;
    int g2N = (TWON + 255) / 256;
    int gInit = (gE > g2N) ? gE : g2N;

    k_init<<<gInit, 256, 0, stream>>>(enc, msk, E, seedA, seedB, cand, hist, deg, scal);
    k_seed<<<(nSeeds + 255) / 256, 256, 0, stream>>>(seeds, nSeeds, seedA);

    unsigned char* cur = seedA;
    unsigned char* nxt = seedB;
    for (int i = 0; i < 3; ++i) {
        k_mark<<<gE, 256, 0, stream>>>(rows, cols, E, cur, enc, msk, cand, (i < 2) ? 1 : 0);
        if (i < 2) {
            // key_i = threefry2x32((0,42), (0,i))  -- fold_in, host-computed
            uint32_t ka, kb;
            tf2x32(0u, 42u, 0u, (uint32_t)i, ka, kb);
            k_score_hist<<<g2N, 256, 0, stream>>>(cand, scores, hist, ka, kb);
            k_scan<<<1, 1024, 0, stream>>>(hist, scal, i);
            k_select<<<g2N, 256, 0, stream>>>(scores, cand, nxt, scal, list);
            k_rank<<<1, 256, 0, stream>>>(scores, list, scal, nxt);
            unsigned char* t = cur; cur = nxt; nxt = t;
        }
    }

    k_deg<<<gE, 256, 0, stream>>>(rows, enc, E, deg);
    k_dinv<<<(NNODES + 255) / 256, 256, 0, stream>>>(deg, dinv);
    k_out<<<gE, 256, 0, stream>>>(rows, cols, E, dinv, enc);
}

// Round 2
// 198.969 us; speedup vs baseline: 1.1074x; 1.1074x over previous
//
#include <hip/hip_runtime.h>
#include <cstdint>

// RandomMaskSubgraphs — R2
//  - alive == !masked (exact complement in the reference), so a single byte
//    array `mk` in ws tracks all edge state; d_out written once at the end.
//  - degree histogram: per-XCD replicas indexed by HW_REG_XCC_ID, updated with
//    workgroup-scope atomics (stay in the local XCD L2 instead of crossing the
//    fabric per-atomic); k_dinv sums the 8 replicas. Sum is XCD-assignment
//    invariant -> deterministic.
//  - all edge-stream kernels vectorized 4 edges/thread (int4 / uint32 / float4).
//  - Threefry-2x32-20 partitionable PRNG + 2048-bin exact k-smallest select
//    (unchanged from the bit-exact R1 version).

#define NNODES 100000
#define TWON   200000
#define NBINS  2048
#define NXCD   8

__host__ __device__ inline uint32_t rotl32(uint32_t v, int d) {
    return (v << d) | (v >> (32 - d));
}

__host__ __device__ inline void tf2x32(uint32_t k0, uint32_t k1,
                                       uint32_t x0, uint32_t x1,
                                       uint32_t& y0, uint32_t& y1) {
    uint32_t k2 = k0 ^ k1 ^ 0x1BD11BDAu;
    x0 += k0; x1 += k1;
    #pragma unroll
    for (int g = 0; g < 5; ++g) {
        const int ra[4] = {13, 15, 26, 6};
        const int rb[4] = {17, 29, 16, 24};
        if ((g & 1) == 0) {
            #pragma unroll
            for (int j = 0; j < 4; ++j) { x0 += x1; x1 = rotl32(x1, ra[j]); x1 ^= x0; }
        } else {
            #pragma unroll
            for (int j = 0; j < 4; ++j) { x0 += x1; x1 = rotl32(x1, rb[j]); x1 ^= x0; }
        }
        uint32_t ks[3] = {k0, k1, k2};
        x0 += ks[(g + 1) % 3];
        x1 += ks[(g + 2) % 3] + (uint32_t)(g + 1);
    }
    y0 = x0; y1 = x1;
}

__device__ inline float uniform_from_bits(uint32_t bits) {
    uint32_t fb = 0x3f800000u | (bits >> 9);
    return __uint_as_float(fb) - 1.0f;
}

__device__ inline uint32_t xcc_id() {
    uint32_t x;
    asm volatile("s_getreg_b32 %0, hwreg(HW_REG_XCC_ID)" : "=s"(x));
    return x & (NXCD - 1);
}

__global__ void k_init(uint32_t* mk32, int E4, int* degrep,
                       uint32_t* seedA32, uint32_t* seedB32, uint32_t* cand32,
                       int* hist, int* scal) {
    int i = blockIdx.x * blockDim.x + threadIdx.x;
    if (i < E4) mk32[i] = 0;                       // E4 == 800000
    if (i < NXCD * NNODES) degrep[i] = 0;          // 800000
    if (i < TWON / 4) { seedA32[i] = 0; seedB32[i] = 0; cand32[i] = 0; }
    if (i < NBINS) hist[i] = 0;
    if (i < 4) scal[i] = (i == 0) ? -1 : 0;
}

__global__ void k_seed(const int* seeds, int n, unsigned char* seedA) {
    int i = blockIdx.x * blockDim.x + threadIdx.x;
    if (i < n) seedA[seeds[i]] = 1;
}

// mark pass with candidate recording (iterations 0,1)
__global__ void k_mark(const int4* __restrict__ r4, const int4* __restrict__ c4,
                       int E4, const unsigned char* __restrict__ sm,
                       uint32_t* __restrict__ mk32, unsigned char* cand) {
    int i = blockIdx.x * blockDim.x + threadIdx.x;
    if (i >= E4) return;
    int4 r = r4[i], c = c4[i];
    uint32_t m = mk32[i];
    uint32_t nm = m;
    if (sm[r.x] | sm[c.x]) { if (!(m & 0x000000FFu)) { nm |= 0x00000001u; cand[r.x + c.x] = 1; } }
    if (sm[r.y] | sm[c.y]) { if (!(m & 0x0000FF00u)) { nm |= 0x00000100u; cand[r.y + c.y] = 1; } }
    if (sm[r.z] | sm[c.z]) { if (!(m & 0x00FF0000u)) { nm |= 0x00010000u; cand[r.z + c.z] = 1; } }
    if (sm[r.w] | sm[c.w]) { if (!(m & 0xFF000000u)) { nm |= 0x01000000u; cand[r.w + c.w] = 1; } }
    if (nm != m) mk32[i] = nm;
}

// final mark pass fused with degree histogram (iteration 2)
__global__ void k_markdeg(const int4* __restrict__ r4, const int4* __restrict__ c4,
                          int E4, const unsigned char* __restrict__ sm,
                          uint32_t* __restrict__ mk32, int* degrep) {
    int i = blockIdx.x * blockDim.x + threadIdx.x;
    if (i >= E4) return;
    int4 r = r4[i], c = c4[i];
    uint32_t m = mk32[i];
    uint32_t nm = m;
    if (sm[r.x] | sm[c.x]) nm |= 0x00000001u;
    if (sm[r.y] | sm[c.y]) nm |= 0x00000100u;
    if (sm[r.z] | sm[c.z]) nm |= 0x00010000u;
    if (sm[r.w] | sm[c.w]) nm |= 0x01000000u;
    if (nm != m) mk32[i] = nm;
    int* myrep = degrep + (int)xcc_id() * NNODES;
    if (!(nm & 0x000000FFu))
        __hip_atomic_fetch_add(&myrep[r.x], 1, __ATOMIC_RELAXED, __HIP_MEMORY_SCOPE_WORKGROUP);
    if (!(nm & 0x0000FF00u))
        __hip_atomic_fetch_add(&myrep[r.y], 1, __ATOMIC_RELAXED, __HIP_MEMORY_SCOPE_WORKGROUP);
    if (!(nm & 0x00FF0000u))
        __hip_atomic_fetch_add(&myrep[r.z], 1, __ATOMIC_RELAXED, __HIP_MEMORY_SCOPE_WORKGROUP);
    if (!(nm & 0xFF000000u))
        __hip_atomic_fetch_add(&myrep[r.w], 1, __ATOMIC_RELAXED, __HIP_MEMORY_SCOPE_WORKGROUP);
}

__global__ void k_score_hist(const unsigned char* __restrict__ cand,
                             float* __restrict__ scores, int* hist,
                             uint32_t ka, uint32_t kb) {
    int s = blockIdx.x * blockDim.x + threadIdx.x;
    if (s >= TWON) return;
    uint32_t y0, y1;
    tf2x32(ka, kb, 0u, (uint32_t)s, y0, y1);
    float u = uniform_from_bits(y0 ^ y1);
    scores[s] = u;
    if (cand[s]) {
        uint32_t b = (uint32_t)(u * 2048.0f);
        if (b > NBINS - 1) b = NBINS - 1;
        atomicAdd(&hist[b], 1);
    }
}

__global__ void k_scan(int* hist, int* scal, int iter) {
    __shared__ int part[1024];
    __shared__ int sT, sR;
    int t = threadIdx.x;
    int h0 = hist[2 * t];
    int h1 = hist[2 * t + 1];
    part[t] = h0 + h1;
    if (t == 0) { sT = -1; sR = 0; }
    __syncthreads();
    for (int d = 1; d < 1024; d <<= 1) {
        int w = (t >= d) ? part[t - d] : 0;
        __syncthreads();
        part[t] += w;
        __syncthreads();
    }
    int total = part[1023];
    int k = total >> (iter + 1);
    int base = (t > 0) ? part[t - 1] : 0;
    if (total > 0) {
        if (h0 > 0 && base <= k && k < base + h0) { sT = 2 * t; sR = k - base; }
        int b2 = base + h0;
        if (h1 > 0 && b2 <= k && k < b2 + h1) { sT = 2 * t + 1; sR = k - b2; }
    }
    __syncthreads();
    if (t == 0) { scal[0] = sT; scal[1] = sR; scal[2] = 0; }
    hist[2 * t] = 0;
    hist[2 * t + 1] = 0;
}

__global__ void k_select(const float* __restrict__ scores, unsigned char* cand,
                         unsigned char* seedB, int* scal, int* list) {
    int s = blockIdx.x * blockDim.x + threadIdx.x;
    if (s >= TWON) return;
    int T = scal[0];
    unsigned char sel = 0;
    if (cand[s]) {
        float u = scores[s];
        int b = (int)(u * 2048.0f);
        if (b > NBINS - 1) b = NBINS - 1;
        if (b < T) sel = 1;
        else if (b == T) {
            int idx = atomicAdd(&scal[2], 1);
            list[idx] = s;
        }
        cand[s] = 0;
    }
    seedB[s] = sel;
}

__global__ void k_rank(const float* __restrict__ scores, const int* __restrict__ list,
                       const int* scal, unsigned char* seedB) {
    int n = scal[2];
    int r = scal[1];
    for (int t = threadIdx.x; t < n; t += blockDim.x) {
        int st = list[t];
        float ut = scores[st];
        int rank = 0;
        for (int j = 0; j < n; ++j) {
            int sj = list[j];
            float uj = scores[sj];
            rank += (uj < ut || (uj == ut && sj < st)) ? 1 : 0;
        }
        if (rank < r) seedB[st] = 1;
    }
}

__global__ void k_dinv(const int* __restrict__ degrep, float* __restrict__ dinv) {
    int n = blockIdx.x * blockDim.x + threadIdx.x;
    if (n >= NNODES) return;
    int d = 0;
    #pragma unroll
    for (int x = 0; x < NXCD; ++x) d += degrep[x * NNODES + n];
    dinv[n] = rsqrtf((float)d + 1e-12f);
}

__global__ void k_out(const int4* __restrict__ r4, const int4* __restrict__ c4,
                      int E4, const uint32_t* __restrict__ mk32,
                      const float* __restrict__ dinv,
                      float4* __restrict__ enc4, float4* __restrict__ msk4) {
    int i = blockIdx.x * blockDim.x + threadIdx.x;
    if (i >= E4) return;
    int4 r = r4[i], c = c4[i];
    uint32_t m = mk32[i];
    float4 ev, mv;
    ev.x = (m & 0x000000FFu) ? 0.0f : dinv[r.x] * dinv[c.x];
    ev.y = (m & 0x0000FF00u) ? 0.0f : dinv[r.y] * dinv[c.y];
    ev.z = (m & 0x00FF0000u) ? 0.0f : dinv[r.z] * dinv[c.z];
    ev.w = (m & 0xFF000000u) ? 0.0f : dinv[r.w] * dinv[c.w];
    mv.x = (m & 0x000000FFu) ? 1.0f : 0.0f;
    mv.y = (m & 0x0000FF00u) ? 1.0f : 0.0f;
    mv.z = (m & 0x00FF0000u) ? 1.0f : 0.0f;
    mv.w = (m & 0xFF000000u) ? 1.0f : 0.0f;
    enc4[i] = ev;
    msk4[i] = mv;
}

extern "C" void kernel_launch(void* const* d_in, const int* in_sizes, int n_in,
                              void* d_out, int out_size, void* d_ws, size_t ws_size,
                              hipStream_t stream) {
    const int* rows  = (const int*)d_in[0];
    const int* cols  = (const int*)d_in[1];
    const int* seeds = (const int*)d_in[3];
    int E      = in_sizes[0];     // 3,200,000 (divisible by 4)
    int nSeeds = in_sizes[3];
    int E4     = E / 4;

    float* enc = (float*)d_out;
    float* msk = enc + E;

    char* p = (char*)d_ws;
    unsigned char* seedA = (unsigned char*)p; p += TWON;
    unsigned char* seedB = (unsigned char*)p; p += TWON;
    unsigned char* cand  = (unsigned char*)p; p += TWON;
    unsigned char* mk    = (unsigned char*)p; p += E;            // 3.2 MB
    float* scores = (float*)p; p += TWON * 4;
    int*   hist   = (int*)p;   p += NBINS * 4;
    int*   degrep = (int*)p;   p += NXCD * NNODES * 4;           // 3.2 MB
    float* dinv   = (float*)p; p += NNODES * 4;
    int*   scal   = (int*)p;   p += 4 * 4;
    int*   list   = (int*)p;   p += TWON * 4;
    // total ws use: ~8.8 MB

    int gE4 = (E4 + 255) / 256;
    int g2N = (TWON + 255) / 256;

    k_init<<<gE4, 256, 0, stream>>>((uint32_t*)mk, E4, degrep,
                                    (uint32_t*)seedA, (uint32_t*)seedB,
                                    (uint32_t*)cand, hist, scal);
    k_seed<<<(nSeeds + 255) / 256, 256, 0, stream>>>(seeds, nSeeds, seedA);

    unsigned char* cur = seedA;
    unsigned char* nxt = seedB;
    for (int i = 0; i < 2; ++i) {
        k_mark<<<gE4, 256, 0, stream>>>((const int4*)rows, (const int4*)cols, E4,
                                        cur, (uint32_t*)mk, cand);
        uint32_t ka, kb;
        tf2x32(0u, 42u, 0u, (uint32_t)i, ka, kb);
        k_score_hist<<<g2N, 256, 0, stream>>>(cand, scores, hist, ka, kb);
        k_scan<<<1, 1024, 0, stream>>>(hist, scal, i);
        k_select<<<g2N, 256, 0, stream>>>(scores, cand, nxt, scal, list);
        k_rank<<<1, 256, 0, stream>>>(scores, list, scal, nxt);
        unsigned char* t = cur; cur = nxt; nxt = t;
    }
    k_markdeg<<<gE4, 256, 0, stream>>>((const int4*)rows, (const int4*)cols, E4,
                                       cur, (uint32_t*)mk, degrep);

    k_dinv<<<(NNODES + 255) / 256, 256, 0, stream>>>(degrep, dinv);
    k_out<<<gE4, 256, 0, stream>>>((const int4*)rows, (const int4*)cols, E4,
                                   (const uint32_t*)mk, dinv,
                                   (float4*)enc, (float4*)msk);
}